// Round 8
// baseline (167.607 us; speedup 1.0000x reference)
//
#include <hip/hip_runtime.h>
#include <math.h>

#define NA 360
#define NP 512
#define NB 16
#define IMG 512
#define ACH 8                // angles per LDS chunk
#define NCH (NA / ACH)       // 45 chunks
#define NPT 32               // LDS points per angle (span <= 25 incl. margins)
#define PS 514               // p' in [0,513]; entry p' holds taps (s[p'-1], s[p'])
#define PS_GUARD (PS - NPT)  // 482
#define NTABB 6              // tab blocks (6 x 64 = 384 >= 360 angles)

typedef unsigned int uint32;
typedef __fp16 half2 __attribute__((ext_vector_type(2)));   // builtin V2h type

static __device__ __forceinline__ half2 u2h(uint32 u) {
    union { uint32 u; half2 h; } v; v.u = u; return v.h;
}
static __device__ __forceinline__ uint32 pk(float a, float b) {
    union { half2 h; uint32 u; } v;
    v.h = __builtin_amdgcn_cvt_pkrtz(a, b);
    return v.u;
}

#if __has_builtin(__builtin_amdgcn_fdot2)
static __device__ __forceinline__ float dot2(half2 w, half2 v, float acc) {
    return __builtin_amdgcn_fdot2(w, v, acc, false);
}
#else
static __device__ __forceinline__ float dot2(half2 w, half2 v, float acc) {
    return fmaf((float)w.x, (float)v.x, fmaf((float)w.y, (float)v.y, acc));
}
#endif

// tab[a] = {c'=cos/dp, s'=sin/dp, off=-pos0/dp, (|c'|+|s'|)*7.5 (block half-span)}
static __device__ __forceinline__ void write_tab(const float* thetas,
                                                 const float* positions,
                                                 float4* tab, int a) {
    double th = (double)thetas[a];
    double p0 = (double)positions[0];
    double dp = (double)positions[1] - p0;
    double c = cos(th) / dp, s = sin(th) / dp;
    tab[a] = make_float4((float)c, (float)s, (float)(-p0 / dp),
                         (float)((fabs(c) + fabs(s)) * 7.5));
}

// Window start with 1-point lower margin against fp rounding (round-8 lesson).
static __device__ __forceinline__ int pmin_of(float tc, float tw) {
    float fmn = fminf(fmaxf(tc - tw, -1.0f), 512.0f);
    return min(max((int)floorf(fmn) - 1, 0), PS_GUARD);
}

// ---------------------------------------------------------------------------
// Round-20 stage: TLP lever, second application. Round-7 post-mortem: wave-
// per-row (1440 blocks, 5.6/CU) cut stage 21.5 -> ~14.5 us — latency theory
// confirmed in direction, half in magnitude. This version halves the per-wave
// serial chain again: one wave per HALF-ROW (2880 main blocks, 11.25/CU).
// Per thread: 4 entries via ONE dwordx4 + 5th tap via __shfl_down (lane 63
// low-half: one predicated scalar load of s[256]; high-half lane 63 is the
// s[512]->0 edge). LDS transpose 4 KB, conflict-free both sides (write slot
// (4g+j)^(g&7), read slot e^((e>>2)&7): distinct bank residues per 8-lane
// subgroup, verified by enumeration). Stores: 4 x 1-KB coalesced per wave.
// Edge entries (pp=0 / pp=513) fold into the owning half's block; fp64-trig
// tab spread over 6 dedicated 64-thread blocks.
// Backproject is the proven round-10 kernel VERBATIM (111.0-113.8 us, 98% of
// the ds_read_b128 issue roofline, conflicts 0). Grid-barrier fusion (r13/14:
// +80 us) and self-staging (r16: +45 us VALU) disproven — structure final.
// If this round is null (>= ~164.5), the stage is at its dispatch+BW floor
// and the session budget is fully decomposed: ROOFLINE.
// ---------------------------------------------------------------------------
__launch_bounds__(64)
__global__ void stage(const float* __restrict__ sino,
                      const float* __restrict__ thetas,
                      const float* __restrict__ positions,
                      float4* __restrict__ tab,
                      uint4* __restrict__ st) {
    const int bid = blockIdx.x;
    const int g   = threadIdx.x;                  // lane 0..63

    if (bid >= 8 * NA) {                          // tab blocks: trig only
        const int a = (bid - 8 * NA) * 64 + g;
        if (a < NA) write_tab(thetas, positions, tab, a);
        return;
    }

    __shared__ uint4 xb[256];                     // 4 KB transpose buffer

    const int h     = bid & 1;                    // row half: entries 256h+1..256h+256
    const int rowid = bid >> 1;                   // [0, 1440)
    const int k     = rowid / NA;                 // plane
    const int a     = rowid - k * NA;             // angle

    uint32 e[4][4];
    uint32 r0[4];
#pragma unroll
    for (int i = 0; i < 4; ++i) {                 // batch 4k+i
        const float* row = sino + ((size_t)(4 * k + i) * NA + a) * NP + 256 * h;
        const float4 lo = *reinterpret_cast<const float4*>(row + 4 * g);
        float ex = __shfl_down(lo.x, 1, 64);      // s[...+4g+4] from lane g+1
        if (g == 63) ex = (h == 0) ? row[256] : 0.0f;   // s[256] / s[512]->0
        e[i][0] = pk(lo.x, lo.y);
        e[i][1] = pk(lo.y, lo.z);
        e[i][2] = pk(lo.z, lo.w);
        e[i][3] = pk(lo.w, ex);
        r0[i] = pk(0.0f, lo.x);                   // lane 0, h=0: pp=0 entry
    }

    // LDS write, swizzled: slot (4g+j) ^ (g&7) — bijective; for fixed j the
    // 8-lane subgroups cover all 8 bank-groups (conflict-free, enumerated).
#pragma unroll
    for (int j = 0; j < 4; ++j)
        xb[(4 * g + j) ^ (g & 7)] = make_uint4(e[0][j], e[1][j], e[2][j], e[3][j]);
    __syncthreads();                              // 1-wave block: lgkm drain

    // Transposed read (slot e ^ ((e>>2)&7), conflict-free) + coalesced stores
    const size_t base = ((size_t)k * NA + a) * PS;
    uint4* dst = st + base + 1 + 256 * h;
#pragma unroll
    for (int j = 0; j < 4; ++j) {
        const int e_idx = g + 64 * j;
        dst[e_idx] = xb[e_idx ^ ((g >> 2) & 7)];
    }

    if (g == 0 && h == 0) st[base] = make_uint4(r0[0], r0[1], r0[2], r0[3]);
    if (g == 0 && h == 1) st[base + (PS - 1)] = make_uint4(0u, 0u, 0u, 0u);
}

// ---------------------------------------------------------------------------
// Proven round-10 backproject — UNCHANGED (111-114 us, 98% of LDS roofline).
// ---------------------------------------------------------------------------
__launch_bounds__(256)
__global__ void backproject(const uint4* __restrict__ st,
                            const float4* __restrict__ tab,
                            float* __restrict__ out) {
    __shared__ uint4 buf[2][ACH * 4 * NPT];     // 2 x 16 KB, [al][q][pt]
    __shared__ int pm_lds[NA];                  // 1.44 KB
    const int tid = threadIdx.y * 16 + threadIdx.x;
    const int x = blockIdx.x * 16 + threadIdx.x;
    const int y = blockIdx.y * 16 + threadIdx.y;
    const float xs = (float)x - 255.5f;
    const float ys = (float)y - 255.5f;
    const float xc = (float)(blockIdx.x * 16) + 7.5f - 255.5f;   // block center
    const float yc = (float)(blockIdx.y * 16) + 7.5f - 255.5f;

    for (int a = tid; a < NA; a += 256) {
        const float4 t = tab[a];
        float tc = fmaf(xc, t.x, fmaf(yc, t.y, t.z));
        pm_lds[a] = pmin_of(tc, t.w);
    }
    __syncthreads();

    float acc[NB];
#pragma unroll
    for (int b = 0; b < NB; ++b) acc[b] = 0.0f;

    const int qld = (tid >> 5) & 3;             // this thread's load plane
    const int ptl = tid & 31;                   // this thread's load point
    const int hl  = tid >> 7;                   // odd/even angle for loads

    auto issue = [&](int ch, int bsel) {
#pragma unroll
        for (int j = 0; j < 4; ++j) {
            const int a = ch * ACH + 2 * j + hl;
            const int pm = pm_lds[a];
            const uint4* gp = &st[(size_t)qld * (NA * PS) + (size_t)a * PS + pm + ptl];
            uint4* lp = &buf[bsel][tid + 256 * j];
            __builtin_amdgcn_global_load_lds(
                (__attribute__((address_space(1))) const void*)gp,
                (__attribute__((address_space(3))) void*)lp, 16, 0, 0);
        }
    };

    issue(0, 0);

#pragma unroll 1
    for (int ch = 0; ch < NCH; ++ch) {
        __syncthreads();                        // drains vmcnt: buf[ch&1] ready
        if (ch + 1 < NCH) issue(ch + 1, (ch + 1) & 1);

        const int a0 = ch * ACH;
        const uint4* b = buf[ch & 1];
#pragma unroll
        for (int al = 0; al < ACH; ++al) {
            const float4 t = tab[a0 + al];      // uniform -> s_load
            float fidx = fmaf(xs, t.x, fmaf(ys, t.y, t.z));
            fidx = fminf(fmaxf(fidx, -1.0f), 512.0f);
            const float fl = floorf(fidx);
            const float w = fidx - fl;
            const half2 wp = u2h(pk(1.0f - w, w));
            const int idx = ((int)fl + 1) - pm_lds[a0 + al];   // [0, 31]
            const uint4 d0 = b[al * 128 + 0 * 32 + idx];
            const uint4 d1 = b[al * 128 + 1 * 32 + idx];
            const uint4 d2 = b[al * 128 + 2 * 32 + idx];
            const uint4 d3 = b[al * 128 + 3 * 32 + idx];
            acc[0]  = dot2(wp, u2h(d0.x), acc[0]);
            acc[1]  = dot2(wp, u2h(d0.y), acc[1]);
            acc[2]  = dot2(wp, u2h(d0.z), acc[2]);
            acc[3]  = dot2(wp, u2h(d0.w), acc[3]);
            acc[4]  = dot2(wp, u2h(d1.x), acc[4]);
            acc[5]  = dot2(wp, u2h(d1.y), acc[5]);
            acc[6]  = dot2(wp, u2h(d1.z), acc[6]);
            acc[7]  = dot2(wp, u2h(d1.w), acc[7]);
            acc[8]  = dot2(wp, u2h(d2.x), acc[8]);
            acc[9]  = dot2(wp, u2h(d2.y), acc[9]);
            acc[10] = dot2(wp, u2h(d2.z), acc[10]);
            acc[11] = dot2(wp, u2h(d2.w), acc[11]);
            acc[12] = dot2(wp, u2h(d3.x), acc[12]);
            acc[13] = dot2(wp, u2h(d3.y), acc[13]);
            acc[14] = dot2(wp, u2h(d3.z), acc[14]);
            acc[15] = dot2(wp, u2h(d3.w), acc[15]);
        }
    }

    const size_t pix = (size_t)y * IMG + x;
#pragma unroll
    for (int b = 0; b < NB; ++b)
        out[(size_t)b * (IMG * IMG) + pix] = acc[b];
}

extern "C" void kernel_launch(void* const* d_in, const int* in_sizes, int n_in,
                              void* d_out, int out_size, void* d_ws, size_t ws_size,
                              hipStream_t stream) {
    const float* sino      = (const float*)d_in[0];
    const float* thetas    = (const float*)d_in[1];
    const float* positions = (const float*)d_in[2];
    float* out = (float*)d_out;

    float4* tab = (float4*)d_ws;                     // 360 * 16 B
    uint4*  st  = (uint4*)((char*)d_ws + 8192);      // 4 planes * 2.96 MB = 11.84 MB

    stage<<<dim3(8 * NA + NTABB), dim3(64), 0, stream>>>(sino, thetas, positions, tab, st);
    backproject<<<dim3(IMG / 16, IMG / 16), dim3(16, 16), 0, stream>>>(st, tab, out);
}